// Round 13
// baseline (3051.714 us; speedup 1.0000x reference)
//
#include <hip/hip_runtime.h>
#include <hip/hip_bf16.h>
#include <math.h>

// ---------------- constants ----------------
#define BB 128
#define FF 243
#define JJ 17
#define ERR 32
#define EE 544
#define EE3 1632
#define NHH 8
#define HDD 68
#define HIDD 1088
#define ROWS 31104          // B*F
#define QSTRIDE 16920576ULL // ROWS*EE
#define GROWS 16            // rows per gc2 block
#define NTM 243             // M tiles (31104/128)

typedef __hip_bfloat16 bf16;
typedef __bf16 bf16x8 __attribute__((ext_vector_type(8)));
typedef float floatx4 __attribute__((ext_vector_type(4)));

static __device__ __forceinline__ float b2f(bf16 v) { return __bfloat162float(v); }
static __device__ __forceinline__ bf16 f2b(float v) { return __float2bfloat16(v); }
static __device__ __forceinline__ unsigned short f2bu(float v) {
    bf16 h = __float2bfloat16(v);
    return *(unsigned short*)&h;
}
// async global->LDS, 16B per lane; dest = wave-uniform base + lane*16
static __device__ __forceinline__ void async16(void* lds, const void* g) {
    __builtin_amdgcn_global_load_lds(
        (const __attribute__((address_space(1))) unsigned*)g,
        (__attribute__((address_space(3))) unsigned*)lds, 16, 0, 0);
}

// ---------------- prep: adjacency softmax + folded q/k projection (parallel) ------
__global__ __launch_bounds__(256) void prep_kernel(
    const float* __restrict__ gc_e, const float* __restrict__ gc_W,
    const float* __restrict__ qw, const float* __restrict__ kw,
    const float* __restrict__ qb, const float* __restrict__ kb,
    float* __restrict__ A, float* __restrict__ Sg)
{
    __shared__ float a1[17][17], a2[17][17], a3[17][17];
    int tid = threadIdx.x;
    const int parents[17] = {-1,0,1,2,0,4,5,0,7,8,9,8,11,12,8,14,15};
    for (int t = tid; t < 289; t += 256) {
        int i = t / 17, j = t % 17;
        bool e = (parents[i] == j) || (parents[j] == i);
        a1[i][j] = e ? 1.f : 0.f;
    }
    __syncthreads();
    for (int t = tid; t < 289; t += 256) {
        int i = t / 17, j = t % 17;
        float s = 0.f;
        #pragma unroll
        for (int k = 0; k < 17; ++k) s += a1[i][k] * a1[k][j];
        a2[i][j] = s;
    }
    __syncthreads();
    for (int t = tid; t < 289; t += 256) {
        int i = t / 17, j = t % 17;
        float s = 0.f;
        #pragma unroll
        for (int k = 0; k < 17; ++k) s += a2[i][k] * a1[k][j];
        a3[i][j] = s;
    }
    __syncthreads();
    for (int p = tid; p < 68; p += 256) {
        int n = p / 17, i = p % 17;
        bool msk[17];
        float m = -1e30f;
        for (int j=0;j<17;++j) {
            bool mm;
            if (n==0) mm = (i==j);
            else if (n==1) mm = a1[i][j] > 0.f;
            else if (n==2) mm = a2[i][j] > 0.f;
            else mm = a3[i][j] > 0.f;
            msk[j] = mm;
            if (mm) m = fmaxf(m, gc_e[(n*17+i)*17+j]);
        }
        float ex[17]; float s=0.f;
        for (int j=0;j<17;++j){ ex[j] = msk[j] ? expf(gc_e[(n*17+i)*17+j]-m) : 0.f; s+=ex[j]; }
        float inv = 1.f/s;
        for (int j=0;j<17;++j) A[(n*17+i)*17+j] = ex[j]*inv;
    }
    if (tid < 256) {
        int c = tid >> 7, n = (tid >> 5) & 3, o2 = tid & 31;
        float s = 0.f;
        for (int o = 0; o < 32; ++o)
            s += gc_W[(n*2+c)*32 + o] * (qw[o*32+o2] + kw[o*32+o2]);
        Sg[tid] = s;
    }
    if (tid < 32) Sg[256 + tid] = qb[tid] + kb[tid];
}

// ---------------- gc2: fused graph conv, 16 rows per block ----------------
__global__ __launch_bounds__(256) void gc2_kernel(
    const float* __restrict__ x, const float* __restrict__ A, const float* __restrict__ Sg,
    const float* __restrict__ gc_W, const float* __restrict__ gc_bias,
    const float* __restrict__ aw, const float* __restrict__ ab,
    const float* __restrict__ lng, const float* __restrict__ lnb,
    const float* __restrict__ pos_embed, float* __restrict__ xe)
{
    __shared__ float As[4][17][17];
    __shared__ float S0[4][33], S1[4][33], bqk[32];
    __shared__ float Ws[4][2][32];
    __shared__ float aws[32], lngs[32], lnbs[32], gbias[32];
    __shared__ float xf[GROWS][34];
    __shared__ float c0[GROWS][68], c1[GROWS][68];
    __shared__ float sc[GROWS][68];
    int tid = threadIdx.x;
    int r0 = blockIdx.x * GROWS;

    for (int i = tid; i < 1156; i += 256) ((float*)As)[i] = A[i];
    if (tid < 128) S0[tid>>5][tid&31] = Sg[tid];
    else           S1[(tid-128)>>5][(tid-128)&31] = Sg[tid];
    if (tid < 32) bqk[tid] = Sg[256+tid];
    if (tid >= 32 && tid < 64)  aws[tid-32]  = aw[tid-32];
    if (tid >= 64 && tid < 96)  lngs[tid-64] = lng[tid-64];
    if (tid >= 96 && tid < 128) lnbs[tid-96] = lnb[tid-96];
    if (tid >= 128 && tid < 160) gbias[tid-128] = gc_bias[tid-128];
    ((float*)Ws)[tid] = gc_W[tid];
    for (int i = tid; i < GROWS*34; i += 256) ((float*)xf)[i] = x[(size_t)r0*34 + i];
    __syncthreads();

    for (int u = tid; u < GROWS*68; u += 256) {
        int row = u / 68, t = u % 68, i = t >> 2, n = t & 3;
        float a0 = 0.f, a1v = 0.f;
        #pragma unroll
        for (int j = 0; j < 17; ++j) {
            float a = As[n][i][j];
            a0  = fmaf(a, xf[row][2*j],   a0);
            a1v = fmaf(a, xf[row][2*j+1], a1v);
        }
        c0[row][t] = a0; c1[row][t] = a1v;
    }
    __syncthreads();

    float abv = ab[0];
    for (int u = tid; u < GROWS*68; u += 256) {
        int row = u / 68, t = u % 68, n = t & 3;
        float v0 = c0[row][t], v1 = c1[row][t];
        float acc = abv;
        #pragma unroll
        for (int o2 = 0; o2 < 32; ++o2) {
            float z = fmaf(v0, S0[n][o2], fmaf(v1, S1[n][o2], bqk[o2]));
            acc = fmaf(tanhf(z), aws[o2], acc);
        }
        sc[row][t] = acc;
    }
    __syncthreads();

    if (tid < GROWS*4) {
        int row = tid >> 2, n = tid & 3;
        float m = -1e30f;
        for (int i = 0; i < 17; ++i) m = fmaxf(m, sc[row][i*4+n]);
        float w[17]; float s = 0.f;
        for (int i = 0; i < 17; ++i) { w[i] = expf(sc[row][i*4+n] - m); s += w[i]; }
        float inv = 1.f / s;
        for (int i = 0; i < 17; ++i) {
            float ww = w[i] * inv;
            c0[row][i*4+n] *= ww;
            c1[row][i*4+n] *= ww;
        }
    }
    __syncthreads();

    int g16 = tid >> 4, lg = tid & 15;
    for (int pair = g16; pair < GROWS*JJ; pair += 16) {
        int row = pair / JJ, j = pair % JJ;
        float e00=c0[row][j*4+0], e01=c0[row][j*4+1], e02=c0[row][j*4+2], e03=c0[row][j*4+3];
        float e10=c1[row][j*4+0], e11=c1[row][j*4+1], e12=c1[row][j*4+2], e13=c1[row][j*4+3];
        int o0 = lg, o1 = lg + 16;
        float a0 = gbias[o0], a1 = gbias[o1];
        a0 = fmaf(e00, Ws[0][0][o0], a0); a0 = fmaf(e10, Ws[0][1][o0], a0);
        a0 = fmaf(e01, Ws[1][0][o0], a0); a0 = fmaf(e11, Ws[1][1][o0], a0);
        a0 = fmaf(e02, Ws[2][0][o0], a0); a0 = fmaf(e12, Ws[2][1][o0], a0);
        a0 = fmaf(e03, Ws[3][0][o0], a0); a0 = fmaf(e13, Ws[3][1][o0], a0);
        a1 = fmaf(e00, Ws[0][0][o1], a1); a1 = fmaf(e10, Ws[0][1][o1], a1);
        a1 = fmaf(e01, Ws[1][0][o1], a1); a1 = fmaf(e11, Ws[1][1][o1], a1);
        a1 = fmaf(e02, Ws[2][0][o1], a1); a1 = fmaf(e12, Ws[2][1][o1], a1);
        a1 = fmaf(e03, Ws[3][0][o1], a1); a1 = fmaf(e13, Ws[3][1][o1], a1);
        float ssum = a0 + a1;
        ssum += __shfl_xor(ssum, 1); ssum += __shfl_xor(ssum, 2);
        ssum += __shfl_xor(ssum, 4); ssum += __shfl_xor(ssum, 8);
        float mu = ssum * (1.f/32.f);
        float d0 = a0 - mu, d1 = a1 - mu;
        float vv = d0*d0 + d1*d1;
        vv += __shfl_xor(vv, 1); vv += __shfl_xor(vv, 2);
        vv += __shfl_xor(vv, 4); vv += __shfl_xor(vv, 8);
        float rstd = rsqrtf(vv*(1.f/32.f) + 1e-5f);
        int r = r0 + row, f = r % FF;
        const float* pe = pos_embed + (size_t)f*EE + j*32;
        float* dst = xe + (size_t)r*EE + j*32;
        dst[o0] = fmaxf(d0*rstd*lngs[o0] + lnbs[o0], 0.f) + pe[o0];
        dst[o1] = fmaxf(d1*rstd*lngs[o1] + lnbs[o1], 0.f) + pe[o1];
    }
}

// ---------------- LN1 + per-joint LN + pooling-score (wave per row, 4 rows/block) --
__global__ __launch_bounds__(256) void ln1_prelude_kernel(
    const float* __restrict__ xe,
    const float* __restrict__ g1, const float* __restrict__ b1,
    const float* __restrict__ ang, const float* __restrict__ anb,
    const float* __restrict__ apw, const float* __restrict__ apb,
    bf16* __restrict__ xr_out, float* __restrict__ s_out)
{
    __shared__ float rowbuf[4][561];     // joint-padded stride 33
    __shared__ float jm[4][17], jrs[4][17];
    __shared__ float angs[32], anbs[32], apws[32];
    int tid = threadIdx.x, w = tid >> 6, lane = tid & 63;
    int r = blockIdx.x*4 + w;
    if (tid < 32) { angs[tid]=ang[tid]; anbs[tid]=anb[tid]; apws[tid]=apw[tid]; }
    float vals[9];
    float ls = 0.f;
    #pragma unroll
    for (int s=0;s<9;++s){ int e=s*64+lane; if(e<EE){ float v=xe[(size_t)r*EE+e]; vals[s]=v; ls+=v; } else vals[s]=0.f; }
    #pragma unroll
    for (int m=1;m<64;m<<=1) ls += __shfl_xor(ls, m);
    float mean = ls*(1.f/544.f);
    float lv = 0.f;
    #pragma unroll
    for (int s=0;s<9;++s){ int e=s*64+lane; if(e<EE){ float d=vals[s]-mean; lv+=d*d; } }
    #pragma unroll
    for (int m=1;m<64;m<<=1) lv += __shfl_xor(lv, m);
    float rstd = rsqrtf(lv*(1.f/544.f)+1e-6f);
    #pragma unroll
    for (int s=0;s<9;++s){ int e=s*64+lane; if(e<EE)
        rowbuf[w][(e>>5)*33+(e&31)] = (vals[s]-mean)*rstd*g1[e] + b1[e]; }
    __syncthreads();
    if (lane < 17) {
        float s0=0.f, s1=0.f;
        for (int o=0;o<32;++o){ float v=rowbuf[w][lane*33+o]; s0+=v; s1+=v*v; }
        float mu = s0*(1.f/32.f);
        jm[w][lane]=mu; jrs[w][lane]=rsqrtf(s1*(1.f/32.f)-mu*mu+1e-5f);
    }
    __syncthreads();
    #pragma unroll
    for (int s=0;s<9;++s){ int e=s*64+lane; if(e<EE){
        int j=e>>5, o=e&31;
        float v = (rowbuf[w][j*33+o]-jm[w][j])*jrs[w][j]*angs[o] + anbs[o];
        xr_out[(size_t)r*EE+e] = f2b(v);
        rowbuf[w][j*33+o] = v; } }
    __syncthreads();
    if (lane < 17) {
        float acc = apb[0];
        for (int o=0;o<32;++o) acc += rowbuf[w][lane*33+o]*apws[o];
        s_out[(size_t)r*JJ+lane] = acc;
    }
}

// ---------------- softmax over frames (wave per (b,joint)) ----------------
__global__ __launch_bounds__(256) void softmax_frames_kernel(float* __restrict__ s)
{
    int tid = threadIdx.x, w = tid >> 6, lane = tid & 63;
    int bid = blockIdx.x*4 + w; int b = bid/JJ, j = bid%JJ;
    float* base = s + (size_t)b*FF*JJ + j;
    float v[4]; float m = -1e30f;
    #pragma unroll
    for (int s2=0;s2<4;++s2){ int e=s2*64+lane;
        v[s2] = (e<FF) ? base[(size_t)e*JJ] : -1e30f;
        m = fmaxf(m, v[s2]); }
    #pragma unroll
    for (int mm=1;mm<64;mm<<=1) m = fmaxf(m, __shfl_xor(m, mm));
    float lsum = 0.f;
    #pragma unroll
    for (int s2=0;s2<4;++s2){ int e=s2*64+lane;
        if (e<FF){ v[s2] = __expf(v[s2]-m); lsum += v[s2]; } }
    #pragma unroll
    for (int mm=1;mm<64;mm<<=1) lsum += __shfl_xor(lsum, mm);
    float inv = 1.f/lsum;
    #pragma unroll
    for (int s2=0;s2<4;++s2){ int e=s2*64+lane;
        if (e<FF) base[(size_t)e*JJ] = v[s2]*inv; }
}

// ---------------- xa = LN544(xr * wf) (wave per row) ----------------
__global__ __launch_bounds__(256) void lnC_kernel(
    const bf16* __restrict__ xr, const float* __restrict__ wf,
    const float* __restrict__ g, const float* __restrict__ b,
    bf16* __restrict__ xa)
{
    __shared__ float wfb[4][17];
    int tid = threadIdx.x, w = tid >> 6, lane = tid & 63;
    int r = blockIdx.x*4 + w;
    if (lane < 17) wfb[w][lane] = wf[(size_t)r*JJ + lane];
    __syncthreads();
    float vals[9]; float ls = 0.f;
    #pragma unroll
    for (int s=0;s<9;++s){ int e=s*64+lane; if(e<EE){
        float v = b2f(xr[(size_t)r*EE+e])*wfb[w][e>>5]; vals[s]=v; ls+=v; } else vals[s]=0.f; }
    #pragma unroll
    for (int m=1;m<64;m<<=1) ls += __shfl_xor(ls, m);
    float mean = ls*(1.f/544.f);
    float lv = 0.f;
    #pragma unroll
    for (int s=0;s<9;++s){ int e=s*64+lane; if(e<EE){ float d=vals[s]-mean; lv+=d*d; } }
    #pragma unroll
    for (int m=1;m<64;m<<=1) lv += __shfl_xor(lv, m);
    float rstd = rsqrtf(lv*(1.f/544.f)+1e-5f);
    #pragma unroll
    for (int s=0;s<9;++s){ int e=s*64+lane; if(e<EE)
        xa[(size_t)r*EE+e] = f2b((vals[s]-mean)*rstd*g[e] + b[e]); }
}

// ---------------- generic LN over 544 (wave per row, no LDS) ----------------
__global__ __launch_bounds__(256) void ln_row_kernel(
    const float* __restrict__ in, const float* __restrict__ g,
    const float* __restrict__ b, bf16* __restrict__ out, float eps)
{
    int tid = threadIdx.x, w = tid >> 6, lane = tid & 63;
    int r = blockIdx.x*4 + w;
    float vals[9]; float ls = 0.f;
    #pragma unroll
    for (int s=0;s<9;++s){ int e=s*64+lane; if(e<EE){ float v=in[(size_t)r*EE+e]; vals[s]=v; ls+=v; } else vals[s]=0.f; }
    #pragma unroll
    for (int m=1;m<64;m<<=1) ls += __shfl_xor(ls, m);
    float mean = ls*(1.f/544.f);
    float lv = 0.f;
    #pragma unroll
    for (int s=0;s<9;++s){ int e=s*64+lane; if(e<EE){ float d=vals[s]-mean; lv+=d*d; } }
    #pragma unroll
    for (int m=1;m<64;m<<=1) lv += __shfl_xor(lv, m);
    float rstd = rsqrtf(lv*(1.f/544.f)+eps);
    #pragma unroll
    for (int s=0;s<9;++s){ int e=s*64+lane; if(e<EE)
        out[(size_t)r*EE+e] = f2b((vals[s]-mean)*rstd*g[e] + b[e]); }
}

// ---------------- weight transpose-convert, coalesced via LDS 32x32 tiles ---------
__global__ __launch_bounds__(256) void wconvT_kernel(
    const float* __restrict__ W, unsigned short* __restrict__ out,
    int N, int K, int Npad)
{
    __shared__ float tile[32][33];
    int bn = blockIdx.x * 32, bk = blockIdx.y * 32;
    int tx = threadIdx.x & 31, ty = threadIdx.x >> 5;   // 32 x 8
    #pragma unroll
    for (int i = 0; i < 4; ++i) {
        int k = bk + ty + i*8, n = bn + tx;
        tile[ty + i*8][tx] = (k < K && n < N) ? W[(size_t)k*N + n] : 0.f;
    }
    __syncthreads();
    #pragma unroll
    for (int i = 0; i < 4; ++i) {
        int n = bn + ty + i*8, k = bk + tx;
        if (n < Npad && k < K) out[(size_t)n*K + k] = f2bu(tile[tx][ty + i*8]);
    }
}

// ---------------- MFMA GEMM, XCD-clustered, BK=64 (halved barrier count) ----------
// main loop: 64-wide LDS rows, swizzle f(r)=r&7 on 8-chunk index (2-way residual);
// K%64 tail: one BK=32 iteration through 32-wide-cast LDS views.
__global__ __launch_bounds__(256) void mgemm_kernel(
    const unsigned short* __restrict__ A, const unsigned short* __restrict__ Bt,
    const float* __restrict__ bias,
    float* __restrict__ out_f32, unsigned short* __restrict__ out_bf,
    int N, int K, int ntn, int mode)
{
    __shared__ unsigned short As[128][64];
    __shared__ unsigned short Bs[128][64];
    int g = blockIdx.x;
    int grp = 8 * ntn;
    int w_ = g % grp, chunk = g / grp;
    int mt = chunk*8 + (w_ & 7), nt = w_ >> 3;
    if (mt >= NTM) return;
    int bm0 = mt * 128, bn0 = nt * 128;
    int tid = threadIdx.x;
    int wave = tid >> 6, lane = tid & 63;
    int wm = (wave >> 1) * 64, wn = (wave & 1) * 64;
    int quad = lane >> 4, l16 = lane & 15;
    int srow0 = wave * 32;
    floatx4 acc[4][4] = {};

    int lr8 = lane >> 3, lc8 = lane & 7;
    int k0 = 0;
    for (; k0 + 64 <= K; k0 += 64) {
        #pragma unroll
        for (int i = 0; i < 4; ++i) {
            int row = srow0 + i*8 + lr8;
            int gch = lc8 ^ (row & 7);
            async16(&As[srow0 + i*8][0], &A [(size_t)(bm0 + row)*K + k0 + gch*8]);
            async16(&Bs[srow0 + i*8][0], &Bt[(size_t)(bn0 + row)*K + k0 + gch*8]);
        }
        __syncthreads();
        #pragma unroll
        for (int kk = 0; kk < 2; ++kk) {
            bf16x8 af[4], bfr[4];
            #pragma unroll
            for (int mi=0;mi<4;++mi) {
                int r = wm + mi*16 + l16;
                af[mi] = *(const bf16x8*)&As[r][((kk*4 + quad) ^ (r & 7))*8];
            }
            #pragma unroll
            for (int ni=0;ni<4;++ni) {
                int r = wn + ni*16 + l16;
                bfr[ni] = *(const bf16x8*)&Bs[r][((kk*4 + quad) ^ (r & 7))*8];
            }
            #pragma unroll
            for (int mi=0;mi<4;++mi)
                #pragma unroll
                for (int ni=0;ni<4;++ni)
                    acc[mi][ni] = __builtin_amdgcn_mfma_f32_16x16x32_bf16(af[mi], bfr[ni], acc[mi][ni], 0, 0, 0);
        }
        __syncthreads();
    }
    if (k0 < K) {   // BK=32 tail (K=544): 32-wide contiguous views over same LDS
        typedef unsigned short (*t32)[32];
        t32 As32 = (t32)&As[0][0];
        t32 Bs32 = (t32)&Bs[0][0];
        int lr = lane >> 2, lc = lane & 3;
        #pragma unroll
        for (int i = 0; i < 2; ++i) {
            int row = srow0 + i*16 + lr;
            int gch = lc ^ ((row >> 1) & 3);
            async16(&As32[srow0 + i*16][0], &A [(size_t)(bm0 + row)*K + k0 + gch*8]);
            async16(&Bs32[srow0 + i*16][0], &Bt[(size_t)(bn0 + row)*K + k0 + gch*8]);
        }
        __syncthreads();
        bf16x8 af[4], bfr[4];
        #pragma unroll
        for (int mi=0;mi<4;++mi) {
            int r = wm + mi*16 + l16;
            af[mi] = *(const bf16x8*)&As32[r][(quad ^ ((r >> 1) & 3))*8];
        }
        #pragma unroll
        for (int ni=0;ni<4;++ni) {
            int r = wn + ni*16 + l16;
            bfr[ni] = *(const bf16x8*)&Bs32[r][(quad ^ ((r >> 1) & 3))*8];
        }
        #pragma unroll
        for (int mi=0;mi<4;++mi)
            #pragma unroll
            for (int ni=0;ni<4;++ni)
                acc[mi][ni] = __builtin_amdgcn_mfma_f32_16x16x32_bf16(af[mi], bfr[ni], acc[mi][ni], 0, 0, 0);
    }

    #pragma unroll
    for (int mi=0;mi<4;++mi) {
        #pragma unroll
        for (int ni=0;ni<4;++ni) {
            #pragma unroll
            for (int r4=0;r4<4;++r4) {
                int gm = bm0 + wm + mi*16 + quad*4 + r4;
                int gn = bn0 + wn + ni*16 + l16;
                if (gn >= N) continue;
                float v = acc[mi][ni][r4] + bias[gn];
                if (mode == 1) {
                    out_bf[(size_t)gm*N + gn] = f2bu(v);
                } else if (mode == 2) {
                    out_f32[(size_t)gm*N + gn] += v;
                } else if (mode == 3) {
                    float g2 = 0.5f * v * (1.0f + erff(v * 0.70710678118654752f));
                    out_bf[(size_t)gm*N + gn] = f2bu(g2);
                } else {
                    out_f32[(size_t)gm*N + gn] = v;
                }
            }
        }
    }
}

// ---------------- MFMA flash attention v3: one block per (b,h) ----------------
__global__ __launch_bounds__(256) void fattn_kernel(
    const unsigned short* __restrict__ qkv,
    const float* __restrict__ scaling_ptr, bf16* __restrict__ ao)
{
    __shared__ unsigned short Ks[256][104];
    __shared__ unsigned short Vt[80][264];    // V transposed [dim][key]
    __shared__ unsigned short Ps[64][264];    // per-wave disjoint rows
    __shared__ float ps_s[256];

    int bh = blockIdx.x, tid = threadIdx.x;
    int b = bh >> 3, h = bh & 7;
    float scaling = scaling_ptr[0];
    const float SCALE = 0.12126781251816648f;  // 68^-0.5

    const unsigned short* base = qkv + (size_t)(b*FF)*EE3;
    const unsigned short* qb_ = base + h*HDD;
    const unsigned short* kb_ = base + EE + h*HDD;
    const unsigned short* vb_ = base + 2*EE + h*HDD;

    if (tid < 256) {
        float pos = tid * (1.0f/242.0f) - 0.5f;
        ps_s[tid] = (tid < FF) ? SCALE * __expf(-scaling * pos * pos) : 0.f;
    }
    for (int idx = tid; idx < 256*18; idx += 256) {
        int r = idx / 18, c2 = idx % 18;
        *(unsigned*)&Ks[r][68 + c2*2] = 0u;
    }
    for (int idx = tid; idx < 80*13; idx += 256) {
        int dd = idx / 13, kk2 = 243 + idx % 13;
        Vt[dd][kk2] = 0;
    }
    for (int idx = tid; idx < FF*34; idx += 256) {
        int r = idx / 34, c2 = idx % 34;
        *(unsigned*)&Ks[r][c2*2] = *(const unsigned*)&kb_[(size_t)r*EE3 + c2*2];
    }
    for (int idx = tid; idx < FF*34; idx += 256) {
        int r = idx / 34, c2 = idx % 34;
        unsigned uv = *(const unsigned*)&vb_[(size_t)r*EE3 + c2*2];
        Vt[c2*2][r]   = (unsigned short)(uv & 0xffffu);
        Vt[c2*2+1][r] = (unsigned short)(uv >> 16);
    }
    __syncthreads();   // the only barrier

    int wave = tid >> 6, lane = tid & 63;
    int quad = lane >> 4, l16 = lane & 15;

    for (int t = 0; t < 4; ++t) {
        int q0 = t * 64;
        int qi = q0 + wave*16 + l16;
        int qc = (qi < FF) ? qi : (FF-1);
        const unsigned short* qrow = qb_ + (size_t)qc*EE3;
        union { bf16x8 v; uint2 u2[2]; unsigned u[4]; } t0, t1, t2;
        t0.u2[0] = *(const uint2*)&qrow[quad*8];
        t0.u2[1] = *(const uint2*)&qrow[quad*8 + 4];
        t1.u2[0] = *(const uint2*)&qrow[32 + quad*8];
        t1.u2[1] = *(const uint2*)&qrow[32 + quad*8 + 4];
        t2.u[0] = 0; t2.u[1] = 0; t2.u[2] = 0; t2.u[3] = 0;
        if (quad == 0) {
            t2.u[0] = *(const unsigned*)&qrow[64];
            t2.u[1] = *(const unsigned*)&qrow[66];
        }
        bf16x8 aq0 = t0.v, aq1 = t1.v, aq2 = t2.v;

        floatx4 sacc[16];
        #pragma unroll
        for (int nt = 0; nt < 16; ++nt) {
            floatx4 c = {};
            c = __builtin_amdgcn_mfma_f32_16x16x32_bf16(aq0, *(const bf16x8*)&Ks[nt*16 + l16][quad*8], c, 0, 0, 0);
            c = __builtin_amdgcn_mfma_f32_16x16x32_bf16(aq1, *(const bf16x8*)&Ks[nt*16 + l16][32 + quad*8], c, 0, 0, 0);
            c = __builtin_amdgcn_mfma_f32_16x16x32_bf16(aq2, *(const bf16x8*)&Ks[nt*16 + l16][64 + quad*8], c, 0, 0, 0);
            sacc[nt] = c;
        }

        float rmax[4] = {-1e30f, -1e30f, -1e30f, -1e30f};
        #pragma unroll
        for (int nt = 0; nt < 16; ++nt) {
            float psc = ps_s[nt*16 + l16];
            bool maskc = (nt*16 + l16) >= FF;
            #pragma unroll
            for (int rg = 0; rg < 4; ++rg) {
                float s = maskc ? -1e30f : sacc[nt][rg] * psc;
                sacc[nt][rg] = s;
                rmax[rg] = fmaxf(rmax[rg], s);
            }
        }
        #pragma unroll
        for (int rg = 0; rg < 4; ++rg) {
            float m0 = rmax[rg];
            m0 = fmaxf(m0, __shfl_xor(m0, 1));
            m0 = fmaxf(m0, __shfl_xor(m0, 2));
            m0 = fmaxf(m0, __shfl_xor(m0, 4));
            m0 = fmaxf(m0, __shfl_xor(m0, 8));
            rmax[rg] = m0;
        }
        float rs[4] = {0.f, 0.f, 0.f, 0.f};
        #pragma unroll
        for (int nt = 0; nt < 16; ++nt)
            #pragma unroll
            for (int rg = 0; rg < 4; ++rg) {
                float p = __expf(sacc[nt][rg] - rmax[rg]);
                sacc[nt][rg] = p;
                rs[rg] += p;
            }
        #pragma unroll
        for (int rg = 0; rg < 4; ++rg) {
            float s0 = rs[rg];
            s0 += __shfl_xor(s0, 1);
            s0 += __shfl_xor(s0, 2);
            s0 += __shfl_xor(s0, 4);
            s0 += __shfl_xor(s0, 8);
            rs[rg] = 1.f / s0;
        }

        #pragma unroll
        for (int nt = 0; nt < 16; ++nt)
            #pragma unroll
            for (int rg = 0; rg < 4; ++rg)
                Ps[wave*16 + quad*4 + rg][nt*16 + l16] = f2bu(sacc[nt][rg] * rs[rg]);

        bf16x8 ap[8];
        #pragma unroll
        for (int kk = 0; kk < 8; ++kk)
            ap[kk] = *(const bf16x8*)&Ps[wave*16 + l16][kk*32 + quad*8];
        #pragma unroll
        for (int nt = 0; nt < 5; ++nt) {
            floatx4 c = {};
            #pragma unroll
            for (int kk = 0; kk < 8; ++kk) {
                bf16x8 bv = *(const bf16x8*)&Vt[nt*16 + l16][kk*32 + quad*8];
                c = __builtin_amdgcn_mfma_f32_16x16x32_bf16(ap[kk], bv, c, 0, 0, 0);
            }
            int gn = nt*16 + l16;
            if (gn < HDD) {
                #pragma unroll
                for (int rg = 0; rg < 4; ++rg) {
                    int query = q0 + wave*16 + quad*4 + rg;
                    if (query < FF)
                        ao[((size_t)b*FF + query)*EE + h*HDD + gn] = f2b(c[rg]);
                }
            }
        }
    }
}

// ---------------- host launch ----------------
extern "C" void kernel_launch(void* const* d_in, const int* in_sizes, int n_in,
                              void* d_out, int out_size, void* d_ws, size_t ws_size,
                              hipStream_t stream) {
    typedef const float* fp;
    fp x          = (fp)d_in[0];
    fp gc_W       = (fp)d_in[2];
    fp gc_e       = (fp)d_in[3];
    fp gc_bias    = (fp)d_in[4];
    fp gc_q_w     = (fp)d_in[5];
    fp gc_q_b     = (fp)d_in[6];
    fp gc_k_w     = (fp)d_in[7];
    fp gc_k_b     = (fp)d_in[8];
    fp gc_attn_w  = (fp)d_in[9];
    fp gc_attn_b  = (fp)d_in[10];
    fp gc_ln_g    = (fp)d_in[11];
    fp gc_ln_b    = (fp)d_in[12];
    fp pos_embed  = (fp)d_in[13];
    fp blk1_g     = (fp)d_in[14];
    fp blk1_b     = (fp)d_in[15];
    fp at_g       = (fp)d_in[16];
    fp at_b       = (fp)d_in[17];
    fp at_pw      = (fp)d_in[18];
    fp at_pb      = (fp)d_in[19];
    fp at2_g      = (fp)d_in[20];
    fp at2_b      = (fp)d_in[21];
    fp at_scaling = (fp)d_in[22];
    fp qkv_w      = (fp)d_in[23];
    fp qkv_b      = (fp)d_in[24];
    fp proj_w     = (fp)d_in[25];
    fp proj_b     = (fp)d_in[26];
    fp blk2_g     = (fp)d_in[27];
    fp blk2_b     = (fp)d_in[28];
    fp fc1_w      = (fp)d_in[29];
    fp fc1_b      = (fp)d_in[30];
    fp fc2_w      = (fp)d_in[31];
    fp fc2_b      = (fp)d_in[32];
    fp fin_g      = (fp)d_in[33];
    fp fin_b      = (fp)d_in[34];
    fp head_w     = (fp)d_in[35];
    fp head_b     = (fp)d_in[36];

    char* wsb = (char*)d_ws;
    size_t off = 0;
    auto alloc = [&](size_t bytes) { size_t cur = off; off += (bytes + 255) & ~(size_t)255; return cur; };
    float* Aw   = (float*)(wsb + alloc(1156 * 4));
    float* Sg   = (float*)(wsb + alloc(288 * 4));
    float* xe   = (float*)(wsb + alloc(QSTRIDE * 4));
    float* sbuf = (float*)(wsb + alloc((size_t)ROWS*JJ * 4));
    bf16*  xr   = (bf16*) (wsb + alloc(QSTRIDE * 2));          // xr; reused as ao
    bf16*  xa   = (bf16*) (wsb + alloc(QSTRIDE * 2));          // xa; reused as xn2/xo
    bf16*  qkv  = (bf16*) (wsb + alloc(3 * QSTRIDE * 2));      // [ROWS][1632] row-major; reused as hm
    unsigned short* wq = (unsigned short*)(wsb + alloc((size_t)1664*544 * 2));
    unsigned short* wp = (unsigned short*)(wsb + alloc((size_t)640*544 * 2));
    unsigned short* w1 = (unsigned short*)(wsb + alloc((size_t)1152*544 * 2));
    unsigned short* w2 = (unsigned short*)(wsb + alloc((size_t)640*1088 * 2));
    (void)ws_size;

    const int CH = 31 * 8;   // ceil(243/8)*8 M-slots

    prep_kernel<<<1, 256, 0, stream>>>(gc_e, gc_W, gc_q_w, gc_k_w, gc_q_b, gc_k_b, Aw, Sg);
    gc2_kernel<<<ROWS/GROWS, 256, 0, stream>>>(
        x, Aw, Sg, gc_W, gc_bias, gc_attn_w, gc_attn_b,
        gc_ln_g, gc_ln_b, pos_embed, xe);
    for (int d = 0; d < 4; ++d) {
        wconvT_kernel<<<dim3(52, 17), 256, 0, stream>>>(
            qkv_w + (size_t)d*EE*3*EE, wq, 1632, 544, 1664);
        wconvT_kernel<<<dim3(20, 17), 256, 0, stream>>>(
            proj_w + (size_t)d*EE*EE, wp, 544, 544, 640);
        wconvT_kernel<<<dim3(36, 17), 256, 0, stream>>>(
            fc1_w + (size_t)d*EE*HIDD, w1, 1088, 544, 1152);
        wconvT_kernel<<<dim3(20, 34), 256, 0, stream>>>(
            fc2_w + (size_t)d*HIDD*EE, w2, 544, 1088, 640);

        ln1_prelude_kernel<<<ROWS/4, 256, 0, stream>>>(
            xe, blk1_g + d*EE, blk1_b + d*EE, at_g + d*ERR, at_b + d*ERR,
            at_pw + d*ERR, at_pb + d, xr, sbuf);
        softmax_frames_kernel<<<BB*JJ/4, 256, 0, stream>>>(sbuf);
        lnC_kernel<<<ROWS/4, 256, 0, stream>>>(xr, sbuf, at2_g + d*EE, at2_b + d*EE, xa);
        mgemm_kernel<<<CH*13, 256, 0, stream>>>(
            (const unsigned short*)xa, wq, qkv_b + d*3*EE,
            nullptr, (unsigned short*)qkv, 1632, 544, 13, 1);
        fattn_kernel<<<BB*NHH, 256, 0, stream>>>(
            (const unsigned short*)qkv, at_scaling + d, xr);
        mgemm_kernel<<<CH*5, 256, 0, stream>>>(
            (const unsigned short*)xr, wp, proj_b + d*EE,
            xe, nullptr, 544, 544, 5, 2);
        ln_row_kernel<<<ROWS/4, 256, 0, stream>>>(xe, blk2_g + d*EE, blk2_b + d*EE, xa, 1e-6f);
        mgemm_kernel<<<CH*9, 256, 0, stream>>>(
            (const unsigned short*)xa, w1, fc1_b + d*HIDD,
            nullptr, (unsigned short*)qkv, 1088, 544, 9, 3);   // hm into qkv region
        mgemm_kernel<<<CH*5, 256, 0, stream>>>(
            (const unsigned short*)qkv, w2, fc2_b + d*EE,
            xe, nullptr, 544, 1088, 5, 2);
    }
    ln_row_kernel<<<ROWS/4, 256, 0, stream>>>(xe, fin_g, fin_b, xa, 1e-6f);
    wconvT_kernel<<<dim3(4, 17), 256, 0, stream>>>(head_w, wq, 51, 544, 128);
    mgemm_kernel<<<CH*1, 256, 0, stream>>>(
        (const unsigned short*)xa, wq, head_b,
        (float*)d_out, nullptr, 51, 544, 1, 4);
}